// Round 6
// baseline (145.200 us; speedup 1.0000x reference)
//
#include <hip/hip_runtime.h>
#include <math.h>

#define HH 512
#define WW 512
#define NB 8
#define NACC 72     // 45 sym AtA + 27 Atb
#define CHUNKS 64   // row-chunks per batch = grid.x
#define NBLK (CHUNKS * NB)

// ---------------------------------------------------------------------------
// Fused kernel: per-pixel SH basis + normal-equation accumulation, then the
// LAST block (device-scope atomic counter) reduces all partials and solves
// the 8 9x9 systems. No cooperative launch needed (R4's grid.sync failed);
// the threadfence-reduction pattern only needs device-scope atomics+fences,
// which are the sanctioned cross-XCD mechanism.
//
// Grid: (CHUNKS, NB) x 256 threads; tx = tid&127 -> 4-px group (aligned
// float4), ty = tid>>7 -> one of 2 rows per pass, 4 passes = 8 rows/block.
//
// __launch_bounds__(256,3): 3 waves/SIMD (VGPR cap ~170; need ~150).
// R1 lesson: default 64-VGPR cap spilled acc[72] -> 249 MB scratch writes.
// R5 analysis: at (256,2) accum is latency-bound at ~2 waves/SIMD; 3 waves
// improves load-latency hiding 1.5x with no spill risk margin ~20 VGPRs.
//
// ws layout: [0..63] floats reserved (counter at ws[0], zeroed by a 64 B
// memset each launch); partials at ws+64: (NB,CHUNKS,NACC) floats.
// ---------------------------------------------------------------------------
__global__ __launch_bounds__(256, 3)
void fused_kernel(const float* __restrict__ img,   // (B,3,H,W)
                  const float* __restrict__ dep,   // (B,1,H,W)
                  const float* __restrict__ alb,   // (B,3,H,W)
                  float* __restrict__ ws,
                  float* __restrict__ out)         // (B,3,9)
{
    // ---- shared declarations (whole kernel) ----
    __shared__ float red[4][NACC];
    __shared__ bool  last_flag;
    __shared__ float allsums[NB][NACC];
    __shared__ float M[NB][9][12];

    unsigned int* cnt  = (unsigned int*)ws;
    float*        part = ws + 64;

    const int b   = blockIdx.y;
    const int tid = threadIdx.x;
    const int tx  = tid & 127;
    const int ty  = tid >> 7;
    const int y0  = blockIdx.x * 8;
    const int x0  = tx * 4;

    // SH constants (double math, constant-folded; PI=3.14159 as reference)
    const float c0 = (float)(3.14159 * sqrt(1.0 / (4.0 * 3.14159)));
    const float c1 = (float)(2.0 * 3.14159 / 3.0 * sqrt(3.0 / (4.0 * 3.14159)));
    const float c2 = (float)(3.14159 / 4.0 * 0.5 * sqrt(5.0 / (4.0 * 3.14159)));
    const float c3 = (float)(3.14159 / 4.0 * 3.0 * sqrt(5.0 / (12.0 * 3.14159)));
    const float c4 = (float)(3.14159 / 4.0 * 3.0 * sqrt(5.0 / (48.0 * 3.14159)));

    float acc[NACC];
#pragma unroll
    for (int i = 0; i < NACC; ++i) acc[i] = 0.0f;

    const float* depb  = dep + (size_t)b * HH * WW;
    const float* img0b = img + (size_t)(b * 3 + 0) * HH * WW;
    const float* img1b = img + (size_t)(b * 3 + 1) * HH * WW;
    const float* img2b = img + (size_t)(b * 3 + 2) * HH * WW;
    const float* alb2b = alb + (size_t)(b * 3 + 2) * HH * WW;

    // fx for x0-1 .. x0+4 (same for every row this thread touches)
    float fxv[6];
#pragma unroll
    for (int k = 0; k < 6; ++k)
        fxv[k] = ((float)(x0 - 1 + k) - 256.0f) / 608.365f;

    for (int pass = 0; pass < 4; ++pass) {
        const int y = y0 + pass * 2 + ty;
        if (y < 1 || y >= HH - 1) continue;   // padded boundary rows

        const int row = y * WW + x0;
        const float fy  = ((float)y       - 256.0f) / 608.365f;
        const float fyd = ((float)(y + 1) - 256.0f) / 608.365f;
        const float fyu = ((float)(y - 1) - 256.0f) / 608.365f;

        // ---- loads (aligned float4 + 2 edge scalars) ----
        const float4 cen4 = *reinterpret_cast<const float4*>(depb + row);
        const float4 up4  = *reinterpret_cast<const float4*>(depb + row - WW);
        const float4 dn4  = *reinterpret_cast<const float4*>(depb + row + WW);
        const float  lsc  = depb[row - (tx == 0 ? 0 : 1)];
        const float  rsc  = depb[row + 4];   // unused when tx==127 (px3 skipped)
        const float4 i04  = *reinterpret_cast<const float4*>(img0b + row);
        const float4 i14  = *reinterpret_cast<const float4*>(img1b + row);
        const float4 i24  = *reinterpret_cast<const float4*>(img2b + row);
        const float4 al4  = *reinterpret_cast<const float4*>(alb2b + row);

        // depth transform (d+1)/2
        float cA[4] = {(cen4.x + 1.0f) * 0.5f, (cen4.y + 1.0f) * 0.5f,
                       (cen4.z + 1.0f) * 0.5f, (cen4.w + 1.0f) * 0.5f};
        float uA[4] = {(up4.x + 1.0f) * 0.5f, (up4.y + 1.0f) * 0.5f,
                       (up4.z + 1.0f) * 0.5f, (up4.w + 1.0f) * 0.5f};
        float dA[4] = {(dn4.x + 1.0f) * 0.5f, (dn4.y + 1.0f) * 0.5f,
                       (dn4.z + 1.0f) * 0.5f, (dn4.w + 1.0f) * 0.5f};
        const float lT = (lsc + 1.0f) * 0.5f;
        const float rT = (rsc + 1.0f) * 0.5f;
        const float g0[4] = {i04.x, i04.y, i04.z, i04.w};
        const float g1[4] = {i14.x, i14.y, i14.z, i14.w};
        const float g2[4] = {i24.x, i24.y, i24.z, i24.w};
        const float aA[4] = {al4.x, al4.y, al4.z, al4.w};

#pragma unroll
        for (int p = 0; p < 4; ++p) {
            const bool valid = !((p == 0 && tx == 0) || (p == 3 && tx == 127));

            const float dc = cA[p];
            const float dl = (p == 0) ? lT : cA[(p == 0) ? 0 : p - 1];
            const float dr = (p == 3) ? rT : cA[(p == 3) ? 3 : p + 1];
            const float du = uA[p];
            const float dd = dA[p];

            const float fx  = fxv[p + 1];
            const float fxl = fxv[p];
            const float fxr = fxv[p + 2];

            // 3D points
            const float pcx = fx  * dc, pcy = fy  * dc;
            const float prx = fxr * dr, pry = fy  * dr;
            const float plx = fxl * dl, ply = fy  * dl;
            const float pdx = fx  * dd, pdy = fyd * dd;
            const float pux = fx  * du, puy = fyu * du;

            // vw = pc-pr ; vs = pd-pc ; ve = pc-pl ; vn = pu-pc
            const float vwx = pcx - prx, vwy = pcy - pry, vwz = dc - dr;
            const float vsx = pdx - pcx, vsy = pdy - pcy, vsz = dd - dc;
            const float vex = pcx - plx, vey = pcy - ply, vez = dc - dl;
            const float vnx = pux - pcx, vny = puy - pcy, vnz = du - dc;

            // normal = cross(vw,vs) + cross(ve,vn)
            const float nx = (vwy * vsz - vwz * vsy) + (vey * vnz - vez * vny);
            const float ny = (vwz * vsx - vwx * vsz) + (vez * vnx - vex * vnz);
            const float nz = (vwx * vsy - vwy * vsx) + (vex * vny - vey * vnx);

            const float nn   = nx * nx + ny * ny + nz * nz;
            const float mag  = sqrtf(nn);
            const float den  = valid ? mag : 1.0f;   // avoid NaN on dead px
            const float invm = 1.0f / den;
            const float uxn = nx * invm, uyn = ny * invm, uzn = nz * invm;
            const float x2 = uxn * uxn, y2 = uyn * uyn, z2 = uzn * uzn;

            const float N0 = c0 * mag;
            const float N1 = c1 * nz;
            const float N2 = c1 * nx;
            const float N3 = c1 * ny;
            const float N4 = c2 * (2.0f * z2 - x2 - y2) * mag;
            const float N5 = c3 * (uxn * uzn) * mag;
            const float N6 = c3 * (uyn * uzn) * mag;
            const float N7 = c4 * (x2 - y2) * mag;
            const float N8 = c3 * (uxn * uyn) * mag;

            // img = (in+1)/2 ; mask = img0 != 0 ; kill dead px via vf
            const float vf = valid ? 1.0f : 0.0f;
            const float i0 = (g0[p] + 1.0f) * 0.5f;
            const float i1 = (g1[p] + 1.0f) * 0.5f;
            const float i2 = (g2[p] + 1.0f) * 0.5f;
            const float m  = ((i0 != 0.0f) ? 1.0f : 0.0f) * vf;
            const float b0 = i0 * m, b1 = i1 * m, b2 = i2 * m;
            const float rho = aA[p] * m;

            const float A[9] = {N0 * rho, N1 * rho, N2 * rho, N3 * rho,
                                N4 * rho, N5 * rho, N6 * rho, N7 * rho,
                                N8 * rho};

            int k = 0;
#pragma unroll
            for (int i = 0; i < 9; ++i)
#pragma unroll
                for (int j = i; j < 9; ++j) {
                    acc[k] = fmaf(A[i], A[j], acc[k]);
                    ++k;
                }
#pragma unroll
            for (int i = 0; i < 9; ++i) {
                acc[45 + i] = fmaf(b0, A[i], acc[45 + i]);
                acc[54 + i] = fmaf(b1, A[i], acc[54 + i]);
                acc[63 + i] = fmaf(b2, A[i], acc[63 + i]);
            }
        }
    }

    // wave butterfly reduce each of the 72 values
#pragma unroll
    for (int i = 0; i < NACC; ++i) {
        float v = acc[i];
        v += __shfl_xor(v, 32, 64);
        v += __shfl_xor(v, 16, 64);
        v += __shfl_xor(v, 8, 64);
        v += __shfl_xor(v, 4, 64);
        v += __shfl_xor(v, 2, 64);
        v += __shfl_xor(v, 1, 64);
        acc[i] = v;
    }

    const int wave = tid >> 6;
    const int lane = tid & 63;
    if (lane == 0) {
#pragma unroll
        for (int i = 0; i < NACC; ++i) red[wave][i] = acc[i];
    }
    __syncthreads();
    if (tid < NACC) {
        const float s = red[0][tid] + red[1][tid] + red[2][tid] + red[3][tid];
        part[((size_t)b * CHUNKS + blockIdx.x) * NACC + tid] = s;
    }

    // ---- last-block detection (threadfence reduction pattern) ----
    __threadfence();                         // release partials (device scope)
    __syncthreads();
    if (tid == 0)
        last_flag = (atomicAdd(cnt, 1u) == NBLK - 1);
    __syncthreads();
    if (!last_flag) return;
    __threadfence();                         // acquire all blocks' partials

    // ---- reduce 64 chunks per batch ----
    for (int bb = 0; bb < NB; ++bb) {
        if (tid < NACC) {
            const float* p = part + (size_t)bb * CHUNKS * NACC + tid;
            float s = 0.0f;
            for (int c = 0; c < CHUNKS; ++c)
                s += p[(size_t)c * NACC];
            allsums[bb][tid] = s;
        }
    }
    __syncthreads();

    // ---- 8 parallel 9x9 solves (threads 0..7), partial-pivot GE ----
    if (tid < NB) {
        const int bb = tid;
        int k = 0;
        for (int i = 0; i < 9; ++i)
            for (int j = i; j < 9; ++j) {
                M[bb][i][j] = allsums[bb][k];
                M[bb][j][i] = allsums[bb][k];
                ++k;
            }
        for (int c = 0; c < 3; ++c)
            for (int i = 0; i < 9; ++i)
                M[bb][i][9 + c] = allsums[bb][45 + c * 9 + i];

        for (int kk = 0; kk < 9; ++kk) {
            int piv = kk;
            float best = fabsf(M[bb][kk][kk]);
            for (int i = kk + 1; i < 9; ++i) {
                const float v = fabsf(M[bb][i][kk]);
                if (v > best) { best = v; piv = i; }
            }
            if (piv != kk)
                for (int j = 0; j < 12; ++j) {
                    const float tmp = M[bb][kk][j];
                    M[bb][kk][j] = M[bb][piv][j];
                    M[bb][piv][j] = tmp;
                }
            const float inv = 1.0f / M[bb][kk][kk];
            for (int i = kk + 1; i < 9; ++i) {
                const float f = M[bb][i][kk] * inv;
                for (int j = kk; j < 12; ++j)
                    M[bb][i][j] -= f * M[bb][kk][j];
            }
        }
        for (int c = 0; c < 3; ++c) {
            float sol[9];
            for (int kk = 8; kk >= 0; --kk) {
                float v = M[bb][kk][9 + c];
                for (int j = kk + 1; j < 9; ++j) v -= M[bb][kk][j] * sol[j];
                sol[kk] = v / M[bb][kk][kk];
            }
            for (int kk = 0; kk < 9; ++kk)
                out[(bb * 3 + c) * 9 + kk] = sol[kk];
        }
    }
}

extern "C" void kernel_launch(void* const* d_in, const int* in_sizes, int n_in,
                              void* d_out, int out_size, void* d_ws, size_t ws_size,
                              hipStream_t stream) {
    const float* img = (const float*)d_in[0];   // input_img  (8,3,512,512)
    const float* dep = (const float*)d_in[1];   // depth_target (8,1,512,512)
    const float* alb = (const float*)d_in[2];   // albedo (8,3,512,512)
    float* out = (float*)d_out;                 // S (8,3,9)
    float* ws  = (float*)d_ws;                  // counter + partials

    // zero the atomic counter region (harness re-poisons ws to 0xAA)
    hipMemsetAsync(ws, 0, 64 * sizeof(float), stream);

    dim3 grid(CHUNKS, NB);
    fused_kernel<<<grid, 256, 0, stream>>>(img, dep, alb, ws, out);
}

// Round 7
// 111.436 us; speedup vs baseline: 1.3030x; 1.3030x over previous
//
#include <hip/hip_runtime.h>
#include <math.h>

#define HH 512
#define WW 512
#define NB 8
#define NACC 72     // 45 sym AtA + 27 Atb
#define CHUNKS 64   // row-chunks per batch = grid.x

// Per-row load bundle: 7 float4 + 2 edge scalars (30 floats).
struct RowData {
    float4 cen, up, dn, i0, i1, i2, al;
    float  lsc, rsc;
};

// ---------------------------------------------------------------------------
// Kernel 1: per-pixel SH basis + normal-equation accumulation.
// Grid: (CHUNKS, NB) x 256 threads; tx = tid&127 -> 4-px group (aligned
// float4), ty = tid>>7 -> one of 2 rows per pass, 4 passes = 8 rows/block.
//
// __launch_bounds__(256,2) is LOAD-BEARING (session history):
//   R1: no bounds -> 64-VGPR cap -> acc[72] spilled to scratch, 249 MB HBM
//       writes, 130 us.
//   R6: (256,3) -> compiler targeted 6 waves/SIMD, 84 VGPRs, AGPR-spill +
//       serial fused tail -> 70 us dispatch, total 145 us. Do not raise.
//   (256,2): ~150 VGPRs, no spill, accum ~13-15 us (near its ~8-10 us
//   max(mem-BW, VALU-issue) floor; vectorization R3 and SW-pipeline R5 were
//   both neutral, confirming it).
// ---------------------------------------------------------------------------
__global__ __launch_bounds__(256, 2)
void accum_kernel(const float* __restrict__ img,   // (B,3,H,W)
                  const float* __restrict__ dep,   // (B,1,H,W)
                  const float* __restrict__ alb,   // (B,3,H,W)
                  float* __restrict__ ws)          // (NB,CHUNKS,72) partials
{
    const int b   = blockIdx.y;
    const int tid = threadIdx.x;
    const int tx  = tid & 127;
    const int ty  = tid >> 7;
    const int y0  = blockIdx.x * 8;
    const int x0  = tx * 4;

    // SH constants (double math, constant-folded; PI=3.14159 as reference)
    const float c0 = (float)(3.14159 * sqrt(1.0 / (4.0 * 3.14159)));
    const float c1 = (float)(2.0 * 3.14159 / 3.0 * sqrt(3.0 / (4.0 * 3.14159)));
    const float c2 = (float)(3.14159 / 4.0 * 0.5 * sqrt(5.0 / (4.0 * 3.14159)));
    const float c3 = (float)(3.14159 / 4.0 * 3.0 * sqrt(5.0 / (12.0 * 3.14159)));
    const float c4 = (float)(3.14159 / 4.0 * 3.0 * sqrt(5.0 / (48.0 * 3.14159)));

    float acc[NACC];
#pragma unroll
    for (int i = 0; i < NACC; ++i) acc[i] = 0.0f;

    const float* depb  = dep + (size_t)b * HH * WW;
    const float* img0b = img + (size_t)(b * 3 + 0) * HH * WW;
    const float* img1b = img + (size_t)(b * 3 + 1) * HH * WW;
    const float* img2b = img + (size_t)(b * 3 + 2) * HH * WW;
    const float* alb2b = alb + (size_t)(b * 3 + 2) * HH * WW;

    // fx for x0-1 .. x0+4 (same for every row this thread touches)
    float fxv[6];
#pragma unroll
    for (int k = 0; k < 6; ++k)
        fxv[k] = ((float)(x0 - 1 + k) - 256.0f) / 608.365f;

    // row indices + validity for the 4 passes
    int  yv[4];
    bool vr[4];
#pragma unroll
    for (int p = 0; p < 4; ++p) {
        const int y = y0 + p * 2 + ty;
        vr[p] = (y >= 1) && (y < HH - 1);
        yv[p] = vr[p] ? y : 1;            // clamp: loads stay in-bounds
    }

    auto load_row = [&](int y) -> RowData {
        RowData r;
        const int row = y * WW + x0;
        r.cen = *reinterpret_cast<const float4*>(depb + row);
        r.up  = *reinterpret_cast<const float4*>(depb + row - WW);
        r.dn  = *reinterpret_cast<const float4*>(depb + row + WW);
        r.lsc = depb[row - (tx == 0 ? 0 : 1)];
        r.rsc = depb[row + 4];
        r.i0  = *reinterpret_cast<const float4*>(img0b + row);
        r.i1  = *reinterpret_cast<const float4*>(img1b + row);
        r.i2  = *reinterpret_cast<const float4*>(img2b + row);
        r.al  = *reinterpret_cast<const float4*>(alb2b + row);
        return r;
    };

    RowData cur = load_row(yv[0]);

#pragma unroll
    for (int pass = 0; pass < 4; ++pass) {
        RowData nxt;
        if (pass < 3) nxt = load_row(yv[pass + 1]);   // prefetch next pass

        if (vr[pass]) {
            const int y = yv[pass];
            const float fy  = ((float)y       - 256.0f) / 608.365f;
            const float fyd = ((float)(y + 1) - 256.0f) / 608.365f;
            const float fyu = ((float)(y - 1) - 256.0f) / 608.365f;

            // depth transform (d+1)/2
            float cA[4] = {(cur.cen.x + 1.0f) * 0.5f, (cur.cen.y + 1.0f) * 0.5f,
                           (cur.cen.z + 1.0f) * 0.5f, (cur.cen.w + 1.0f) * 0.5f};
            float uA[4] = {(cur.up.x + 1.0f) * 0.5f, (cur.up.y + 1.0f) * 0.5f,
                           (cur.up.z + 1.0f) * 0.5f, (cur.up.w + 1.0f) * 0.5f};
            float dA[4] = {(cur.dn.x + 1.0f) * 0.5f, (cur.dn.y + 1.0f) * 0.5f,
                           (cur.dn.z + 1.0f) * 0.5f, (cur.dn.w + 1.0f) * 0.5f};
            const float lT = (cur.lsc + 1.0f) * 0.5f;
            const float rT = (cur.rsc + 1.0f) * 0.5f;
            const float g0[4] = {cur.i0.x, cur.i0.y, cur.i0.z, cur.i0.w};
            const float g1[4] = {cur.i1.x, cur.i1.y, cur.i1.z, cur.i1.w};
            const float g2[4] = {cur.i2.x, cur.i2.y, cur.i2.z, cur.i2.w};
            const float aA[4] = {cur.al.x, cur.al.y, cur.al.z, cur.al.w};

#pragma unroll
            for (int p = 0; p < 4; ++p) {
                const bool valid = !((p == 0 && tx == 0) || (p == 3 && tx == 127));

                const float dc = cA[p];
                const float dl = (p == 0) ? lT : cA[(p == 0) ? 0 : p - 1];
                const float dr = (p == 3) ? rT : cA[(p == 3) ? 3 : p + 1];
                const float du = uA[p];
                const float dd = dA[p];

                const float fx  = fxv[p + 1];
                const float fxl = fxv[p];
                const float fxr = fxv[p + 2];

                // 3D points
                const float pcx = fx  * dc, pcy = fy  * dc;
                const float prx = fxr * dr, pry = fy  * dr;
                const float plx = fxl * dl, ply = fy  * dl;
                const float pdx = fx  * dd, pdy = fyd * dd;
                const float pux = fx  * du, puy = fyu * du;

                // vw = pc-pr ; vs = pd-pc ; ve = pc-pl ; vn = pu-pc
                const float vwx = pcx - prx, vwy = pcy - pry, vwz = dc - dr;
                const float vsx = pdx - pcx, vsy = pdy - pcy, vsz = dd - dc;
                const float vex = pcx - plx, vey = pcy - ply, vez = dc - dl;
                const float vnx = pux - pcx, vny = puy - pcy, vnz = du - dc;

                // normal = cross(vw,vs) + cross(ve,vn)
                const float nx = (vwy * vsz - vwz * vsy) + (vey * vnz - vez * vny);
                const float ny = (vwz * vsx - vwx * vsz) + (vez * vnx - vex * vnz);
                const float nz = (vwx * vsy - vwy * vsx) + (vex * vny - vey * vnx);

                const float nn   = nx * nx + ny * ny + nz * nz;
                const float mag  = sqrtf(nn);
                const float den  = valid ? mag : 1.0f;   // avoid NaN on dead px
                const float invm = 1.0f / den;
                const float uxn = nx * invm, uyn = ny * invm, uzn = nz * invm;
                const float x2 = uxn * uxn, y2 = uyn * uyn, z2 = uzn * uzn;

                const float N0 = c0 * mag;
                const float N1 = c1 * nz;
                const float N2 = c1 * nx;
                const float N3 = c1 * ny;
                const float N4 = c2 * (2.0f * z2 - x2 - y2) * mag;
                const float N5 = c3 * (uxn * uzn) * mag;
                const float N6 = c3 * (uyn * uzn) * mag;
                const float N7 = c4 * (x2 - y2) * mag;
                const float N8 = c3 * (uxn * uyn) * mag;

                // img = (in+1)/2 ; mask = img0 != 0 ; kill dead px via vf
                const float vf = valid ? 1.0f : 0.0f;
                const float i0 = (g0[p] + 1.0f) * 0.5f;
                const float i1 = (g1[p] + 1.0f) * 0.5f;
                const float i2 = (g2[p] + 1.0f) * 0.5f;
                const float m  = ((i0 != 0.0f) ? 1.0f : 0.0f) * vf;
                const float b0 = i0 * m, b1 = i1 * m, b2 = i2 * m;
                const float rho = aA[p] * m;

                const float A[9] = {N0 * rho, N1 * rho, N2 * rho, N3 * rho,
                                    N4 * rho, N5 * rho, N6 * rho, N7 * rho,
                                    N8 * rho};

                int k = 0;
#pragma unroll
                for (int i = 0; i < 9; ++i)
#pragma unroll
                    for (int j = i; j < 9; ++j) {
                        acc[k] = fmaf(A[i], A[j], acc[k]);
                        ++k;
                    }
#pragma unroll
                for (int i = 0; i < 9; ++i) {
                    acc[45 + i] = fmaf(b0, A[i], acc[45 + i]);
                    acc[54 + i] = fmaf(b1, A[i], acc[54 + i]);
                    acc[63 + i] = fmaf(b2, A[i], acc[63 + i]);
                }
            }
        }
        cur = nxt;
    }

    // wave butterfly reduce each of the 72 values
#pragma unroll
    for (int i = 0; i < NACC; ++i) {
        float v = acc[i];
        v += __shfl_xor(v, 32, 64);
        v += __shfl_xor(v, 16, 64);
        v += __shfl_xor(v, 8, 64);
        v += __shfl_xor(v, 4, 64);
        v += __shfl_xor(v, 2, 64);
        v += __shfl_xor(v, 1, 64);
        acc[i] = v;
    }

    __shared__ float red[4][NACC];
    const int wave = tid >> 6;
    const int lane = tid & 63;
    if (lane == 0) {
#pragma unroll
        for (int i = 0; i < NACC; ++i) red[wave][i] = acc[i];
    }
    __syncthreads();
    if (tid < NACC) {
        const float s = red[0][tid] + red[1][tid] + red[2][tid] + red[3][tid];
        ws[((size_t)b * CHUNKS + blockIdx.x) * NACC + tid] = s;  // no atomics
    }
}

// ---------------------------------------------------------------------------
// Kernel 2: reduce the 64 per-chunk partials, then 9x9 solve w/ 3 RHS
// (partial-pivot Gaussian elim, matching jnp.linalg.solve LU behavior).
// One block per batch. Output S is (B,3,9).
// ---------------------------------------------------------------------------
__global__ void solve_kernel(const float* __restrict__ ws, float* __restrict__ out)
{
    __shared__ float sums[NACC];
    __shared__ float M[9][12];
    const int b = blockIdx.x;
    const int t = threadIdx.x;

    if (t < NACC) {
        float s = 0.0f;
        for (int c = 0; c < CHUNKS; ++c)
            s += ws[((size_t)b * CHUNKS + c) * NACC + t];
        sums[t] = s;
    }
    __syncthreads();

    if (t == 0) {
        int k = 0;
        for (int i = 0; i < 9; ++i)
            for (int j = i; j < 9; ++j) {
                M[i][j] = sums[k];
                M[j][i] = sums[k];
                ++k;
            }
        for (int c = 0; c < 3; ++c)
            for (int i = 0; i < 9; ++i)
                M[i][9 + c] = sums[45 + c * 9 + i];

        // forward elimination with partial pivoting
        for (int kk = 0; kk < 9; ++kk) {
            int piv = kk;
            float best = fabsf(M[kk][kk]);
            for (int i = kk + 1; i < 9; ++i) {
                const float v = fabsf(M[i][kk]);
                if (v > best) { best = v; piv = i; }
            }
            if (piv != kk)
                for (int j = 0; j < 12; ++j) {
                    const float tmp = M[kk][j];
                    M[kk][j] = M[piv][j];
                    M[piv][j] = tmp;
                }
            const float inv = 1.0f / M[kk][kk];
            for (int i = kk + 1; i < 9; ++i) {
                const float f = M[i][kk] * inv;
                for (int j = kk; j < 12; ++j)
                    M[i][j] -= f * M[kk][j];
            }
        }
        // back substitution
        for (int c = 0; c < 3; ++c) {
            float sol[9];
            for (int kk = 8; kk >= 0; --kk) {
                float v = M[kk][9 + c];
                for (int j = kk + 1; j < 9; ++j) v -= M[kk][j] * sol[j];
                sol[kk] = v / M[kk][kk];
            }
            for (int kk = 0; kk < 9; ++kk)
                out[(b * 3 + c) * 9 + kk] = sol[kk];
        }
    }
}

extern "C" void kernel_launch(void* const* d_in, const int* in_sizes, int n_in,
                              void* d_out, int out_size, void* d_ws, size_t ws_size,
                              hipStream_t stream) {
    const float* img = (const float*)d_in[0];   // input_img  (8,3,512,512)
    const float* dep = (const float*)d_in[1];   // depth_target (8,1,512,512)
    const float* alb = (const float*)d_in[2];   // albedo (8,3,512,512)
    float* out = (float*)d_out;                 // S (8,3,9)
    float* ws  = (float*)d_ws;                  // 8*64*72 partial floats

    dim3 grid(CHUNKS, NB);
    accum_kernel<<<grid, 256, 0, stream>>>(img, dep, alb, ws);
    solve_kernel<<<NB, 128, 0, stream>>>(ws, out);
}